// Round 6
// baseline (1841.108 us; speedup 1.0000x reference)
//
#include <hip/hip_runtime.h>

#define T_STEPS 365
#define XLEN    (T_STEPS * 3)
#define H_SZ    256
#define ROWS    16
#define NW      4      // waves per block (1 per SIMD -> 512-reg budget)
#define CPW     64     // state cols per wave

typedef __attribute__((ext_vector_type(8))) short bf16x8;   // 8 bf16 = 4 VGPRs
typedef __attribute__((ext_vector_type(4))) short bf16x4;   // 4 bf16 = 2 VGPRs
typedef __attribute__((ext_vector_type(4))) float f32x4;

__device__ __forceinline__ float fast_sigmoid(float x) {
    return __builtin_amdgcn_rcpf(1.0f + __builtin_amdgcn_exp2f(-1.44269504f * x));
}
__device__ __forceinline__ float fast_tanh(float x) {
    return 2.0f * __builtin_amdgcn_rcpf(1.0f + __builtin_amdgcn_exp2f(-2.88539008f * x)) - 1.0f;
}
__device__ __forceinline__ unsigned short f2bf(float x) {   // fp32 -> bf16 RTNE
    unsigned int u = __float_as_uint(x);
    u = (u + 0x7FFFu + ((u >> 16) & 1u)) >> 16;
    return (unsigned short)u;
}
__device__ __forceinline__ bf16x8 expand4(bf16x4 v) {       // {v0..v3,0,0,0,0}
    bf16x8 r = (bf16x8)0;
    r[0] = v[0]; r[1] = v[1]; r[2] = v[2]; r[3] = v[3];
    return r;
}

// One block = 4 waves = 16 batch rows x all 256 state cols; wave owns 64 cols.
// Transposed MFMA (round-4-verified maps): D[c][r] = sum_k W^T[c][k] hx^T[k][r].
// Weights: 96 bf16x8 h-frags (384 regs) + 12 bf16x4 x-frags (24 regs, expanded
// to zero-padded bf16x8 transiently per MFMA). Intrinsic MFMAs only.
__global__ void __launch_bounds__(256, 1)
ealstm_fused(const float* __restrict__ x_dyn, const float* __restrict__ x_stat,
             const float* __restrict__ w_i, const float* __restrict__ b_i,
             const float* __restrict__ w_f, const float* __restrict__ b_f,
             const float* __restrict__ w_g, const float* __restrict__ b_g,
             const float* __restrict__ w_o, const float* __restrict__ b_o,
             const float* __restrict__ w_head, const float* __restrict__ b_head,
             float* __restrict__ out)
{
    const int tid   = threadIdx.x;
    const int lane  = tid & 63;
    const int wv    = tid >> 6;       // 0..3
    const int m     = lane & 15;      // batch row (N dim of D)
    const int l16   = lane >> 4;      // 0..3
    const int rb    = blockIdx.x * ROWS;
    const int wbase = wv * CPW;

    __shared__ unsigned short hbuf[2][4096];       // 2 x 8 KB h^T B-pack
    __shared__ unsigned short xpack[T_STEPS][64];  // [t][r*4+e]={x0,x1,x2,1} bf16
    __shared__ float          red[NW][ROWS];

    // ---- one-time staging ----
    for (int idx = tid; idx < T_STEPS * ROWS; idx += 256) {
        const int t = idx % T_STEPS, r = idx / T_STEPS;
        const float* s = x_dyn + (size_t)(rb + r) * XLEN + t * 3;
        bf16x4 pk;
        pk[0] = (short)f2bf(s[0]); pk[1] = (short)f2bf(s[1]);
        pk[2] = (short)f2bf(s[2]); pk[3] = (short)0x3F80;      // 1.0 bf16
        *(bf16x4*)&xpack[t][r * 4] = pk;
    }
    for (int idx = tid; idx < 2048; idx += 256) ((unsigned int*)hbuf[0])[idx] = 0u;

    const float* wsrc[3] = {w_f, w_g, w_o};
    const float* bsrc[3] = {b_f, b_g, b_o};

    // ---- weights -> registers ----
    // A map (K=32): lane holds A[c = wbase+ct*16+(lane&15)][k' = l16*8+e].
    // x-tile A-frag: nonzero only l16==0, e<4 (k'=0..3: Wx rows 0..2 + bias).
    bf16x8 wA[8][4][3];
    bf16x4 wX[4][3];
#pragma unroll
    for (int ct = 0; ct < 4; ++ct) {
        const int c = wbase + ct * 16 + m;
#pragma unroll
        for (int g = 0; g < 3; ++g) {
#pragma unroll
            for (int kt = 0; kt < 8; ++kt) {
                bf16x8 a;
#pragma unroll
                for (int e = 0; e < 8; ++e)
                    a[e] = (short)f2bf(wsrc[g][(3 + kt * 32 + l16 * 8 + e) * H_SZ + c]);
                wA[kt][ct][g] = a;
            }
            bf16x4 ax = (bf16x4)0;
            if (l16 == 0) {
                ax[0] = (short)f2bf(wsrc[g][0 * H_SZ + c]);
                ax[1] = (short)f2bf(wsrc[g][1 * H_SZ + c]);
                ax[2] = (short)f2bf(wsrc[g][2 * H_SZ + c]);
                ax[3] = (short)f2bf(bsrc[g][c]);
            }
            wX[ct][g] = ax;
        }
    }

    // ---- static input gate (bf16-packed, 8 regs) + cell state ----
    unsigned int ivp[4][2];
    float cst[4][4];
    {
        const float xs0 = x_stat[(rb + m) * 3 + 0];
        const float xs1 = x_stat[(rb + m) * 3 + 1];
        const float xs2 = x_stat[(rb + m) * 3 + 2];
#pragma unroll
        for (int ct = 0; ct < 4; ++ct) {
            float ivq[4];
#pragma unroll
            for (int q = 0; q < 4; ++q) {
                const int c = wbase + ct * 16 + l16 * 4 + q;
                ivq[q] = fast_sigmoid(b_i[c] + xs0 * w_i[c] + xs1 * w_i[H_SZ + c]
                                             + xs2 * w_i[2 * H_SZ + c]);
                cst[ct][q] = 0.0f;
            }
            ivp[ct][0] = (unsigned)f2bf(ivq[0]) | ((unsigned)f2bf(ivq[1]) << 16);
            ivp[ct][1] = (unsigned)f2bf(ivq[2]) | ((unsigned)f2bf(ivq[3]) << 16);
        }
    }

    // h-write offsets: c0 = wbase+ct*16+l16*4; kt=c0>>5; L=m+16*((c0&31)>>3); e=c0&7
    int woff[4];
#pragma unroll
    for (int ct = 0; ct < 4; ++ct) {
        const int c0 = wbase + ct * 16 + l16 * 4;
        woff[ct] = ((c0 >> 5) * 64 + m + 16 * ((c0 & 31) >> 3)) * 8 + (c0 & 7);
    }

    __syncthreads();

    for (int t = 0; t < T_STEPS; ++t) {
        const int cur = t & 1;

        // x B-frag (K=32, round-4-proven): lane holds B[k'=l16*8+e][r=m];
        // nonzero only l16==0, e<4.
        bf16x8 xf = (bf16x8)0;
        {
            const bf16x4 v = *(const bf16x4*)&xpack[t][m * 4];
            if (l16 == 0) { xf[0] = v[0]; xf[1] = v[1]; xf[2] = v[2]; xf[3] = v[3]; }
        }

        // acc init via x-tile MFMA (expand wX transiently: 4-reg live range)
        f32x4 acc[4][3];
        {
            const f32x4 z4 = {0.f, 0.f, 0.f, 0.f};
#pragma unroll
            for (int ct = 0; ct < 4; ++ct)
#pragma unroll
                for (int g = 0; g < 3; ++g)
                    acc[ct][g] = __builtin_amdgcn_mfma_f32_16x16x32_bf16(
                        expand4(wX[ct][g]), xf, z4, 0, 0, 0);
        }

        // z += h @ Wh : stream B-frags, 8 kt
        const bf16x8* hp = (const bf16x8*)hbuf[cur];
#pragma unroll
        for (int kt = 0; kt < 8; ++kt) {
            const bf16x8 b = hp[kt * 64 + lane];
#pragma unroll
            for (int ct = 0; ct < 4; ++ct)
#pragma unroll
                for (int g = 0; g < 3; ++g)
                    acc[ct][g] = __builtin_amdgcn_mfma_f32_16x16x32_bf16(
                        wA[kt][ct][g], b, acc[ct][g], 0, 0, 0);
        }

        // gates + state; h -> LDS (b64 contiguous); always write (head reads back)
        unsigned short* hw = hbuf[cur ^ 1];
#pragma unroll
        for (int ct = 0; ct < 4; ++ct) {
            const float ivq[4] = {
                __uint_as_float(ivp[ct][0] << 16),
                __uint_as_float(ivp[ct][0] & 0xffff0000u),
                __uint_as_float(ivp[ct][1] << 16),
                __uint_as_float(ivp[ct][1] & 0xffff0000u)};
            bf16x4 pk;
#pragma unroll
            for (int q = 0; q < 4; ++q) {
                const float fq = fast_sigmoid(acc[ct][0][q]);
                const float gq = fast_tanh(acc[ct][1][q]);
                const float oq = fast_sigmoid(acc[ct][2][q]);
                const float cq = fq * cst[ct][q] + ivq[q] * gq;
                cst[ct][q] = cq;
                pk[q] = (short)f2bf(oq * fast_tanh(cq));
            }
            *(bf16x4*)&hw[woff[ct]] = pk;
        }
        __syncthreads();
    }

    // ---- head: out[r] = sum_c h[r][c] w_head[c] + b_head ----
    float p = 0.0f;
    const unsigned short* hf = hbuf[1];   // t=364 wrote buf (364&1)^1 = 1
#pragma unroll
    for (int ct = 0; ct < 4; ++ct) {
        const int c0 = wbase + ct * 16 + l16 * 4;
        const f32x4 wh = *(const f32x4*)&w_head[c0];
        const bf16x4 hv = *(const bf16x4*)&hf[woff[ct]];
#pragma unroll
        for (int q = 0; q < 4; ++q)
            p += __uint_as_float(((unsigned)(unsigned short)hv[q]) << 16) * wh[q];
    }
    p += __shfl_xor(p, 16);
    p += __shfl_xor(p, 32);
    if (lane < 16) red[wv][m] = p;
    __syncthreads();
    if (tid < ROWS) {
        float s = b_head[0];
#pragma unroll
        for (int w = 0; w < NW; ++w) s += red[w][tid];
        out[rb + tid] = s;
    }
}

extern "C" void kernel_launch(void* const* d_in, const int* in_sizes, int n_in,
                              void* d_out, int out_size, void* d_ws, size_t ws_size,
                              hipStream_t stream)
{
    const float* x_dyn  = (const float*)d_in[0];
    const float* x_stat = (const float*)d_in[1];
    const float* w_i    = (const float*)d_in[2];
    const float* b_i    = (const float*)d_in[3];
    const float* w_f    = (const float*)d_in[4];
    const float* b_f    = (const float*)d_in[5];
    const float* w_g    = (const float*)d_in[6];
    const float* b_g    = (const float*)d_in[7];
    const float* w_o    = (const float*)d_in[8];
    const float* b_o    = (const float*)d_in[9];
    const float* w_head = (const float*)d_in[10];
    const float* b_head = (const float*)d_in[11];

    ealstm_fused<<<dim3(64), dim3(256), 0, stream>>>(
        x_dyn, x_stat, w_i, b_i, w_f, b_f, w_g, b_g, w_o, b_o,
        w_head, b_head, (float*)d_out);
}

// Round 7
// 827.892 us; speedup vs baseline: 2.2238x; 2.2238x over previous
//
#include <hip/hip_runtime.h>

#define T_STEPS 365
#define XLEN    (T_STEPS * 3)
#define H_SZ    256
#define ROWS    16
#define NW      8      // waves per block (2 per SIMD -> 256-reg budget)
#define CPW     32     // state cols per wave

typedef __attribute__((ext_vector_type(8))) short bf16x8;   // 8 bf16 = 4 VGPRs
typedef __attribute__((ext_vector_type(4))) short bf16x4;   // 4 bf16 = 2 VGPRs
typedef __attribute__((ext_vector_type(4))) float f32x4;

__device__ __forceinline__ float fast_sigmoid(float x) {
    return __builtin_amdgcn_rcpf(1.0f + __builtin_amdgcn_exp2f(-1.44269504f * x));
}
__device__ __forceinline__ float fast_tanh(float x) {
    return 2.0f * __builtin_amdgcn_rcpf(1.0f + __builtin_amdgcn_exp2f(-2.88539008f * x)) - 1.0f;
}
__device__ __forceinline__ unsigned short f2bf(float x) {   // fp32 -> bf16 RTNE
    unsigned int u = __float_as_uint(x);
    u = (u + 0x7FFFu + ((u >> 16) & 1u)) >> 16;
    return (unsigned short)u;
}
__device__ __forceinline__ float bf2f(unsigned short v) {
    return __uint_as_float(((unsigned)v) << 16);
}

// One block = 8 waves = 16 batch rows x all 256 state cols; wave owns 32 cols.
// Transposed MFMA (proven maps): D[c][r] = sum_k W^T[c][k] h^T[k][r].
// Register budget engineered to < 256 (2 waves/SIMD):
//   regs: wA f,g gates only = 32 frags = 128 regs (+acc 24, cst 8, ivp 4, misc)
//   LDS : o-gate Wh as A-frags (128 KB), Wx/bias coef table (12 KB),
//         hbuf double-buffer (16 KB), reduce scratch. Total 156.5 KiB.
// x-tile MFMA eliminated: acc init on VALU from LDS coefs + prefetched fp32 x.
__global__ void __launch_bounds__(512, 2)
ealstm_fused(const float* __restrict__ x_dyn, const float* __restrict__ x_stat,
             const float* __restrict__ w_i, const float* __restrict__ b_i,
             const float* __restrict__ w_f, const float* __restrict__ b_f,
             const float* __restrict__ w_g, const float* __restrict__ b_g,
             const float* __restrict__ w_o, const float* __restrict__ b_o,
             const float* __restrict__ w_head, const float* __restrict__ b_head,
             float* __restrict__ out)
{
    const int tid   = threadIdx.x;
    const int lane  = tid & 63;
    const int wv    = tid >> 6;       // 0..7
    const int m     = lane & 15;      // batch row (N dim of D)
    const int l16   = lane >> 4;      // 0..3
    const int rb    = blockIdx.x * ROWS;
    const int wbase = wv * CPW;

    __shared__ unsigned short wo_lds[8 * 4 * 256 * 8]; // 128 KB [kt][l16][c][e]
    __shared__ unsigned short hbuf[2][4096];           // 16 KB h^T B-pack, dbuf
    __shared__ f32x4          wxlds[3][H_SZ];          // 12 KB {w0,w1,w2,b}
    __shared__ float          red[NW][ROWS];

    const float* wsrc[3] = {w_f, w_g, w_o};
    const float* bsrc[3] = {b_f, b_g, b_o};

    // ---- one-time staging ----
    // o-gate Wh -> LDS A-frags (c-coalesced reads)
    for (int idx = tid; idx < 8 * 4 * 8 * 256; idx += 512) {
        const int c    = idx & 255;
        const int e    = (idx >> 8) & 7;
        const int l16g = (idx >> 11) & 3;
        const int kt   = idx >> 13;
        wo_lds[((kt * 4 + l16g) * 256 + c) * 8 + e] =
            f2bf(w_o[(3 + kt * 32 + l16g * 8 + e) * H_SZ + c]);
    }
    // Wx/bias coef table
    for (int idx = tid; idx < 3 * H_SZ; idx += 512) {
        const int g = idx >> 8, c = idx & 255;
        f32x4 v;
        v[0] = wsrc[g][c]; v[1] = wsrc[g][H_SZ + c];
        v[2] = wsrc[g][2 * H_SZ + c]; v[3] = bsrc[g][c];
        wxlds[g][c] = v;
    }
    // zero h^{-1}
    for (int idx = tid; idx < 2048; idx += 512) ((unsigned int*)hbuf[0])[idx] = 0u;

    // f,g-gate Wh slices -> registers (32 frags = 128 regs)
    // A map: lane holds A[c = wbase+ct*16+(lane&15)][k' = l16*8+e]
    bf16x8 wA[8][2][2];
#pragma unroll
    for (int ct = 0; ct < 2; ++ct) {
        const int c = wbase + ct * 16 + m;
#pragma unroll
        for (int g = 0; g < 2; ++g)
#pragma unroll
            for (int kt = 0; kt < 8; ++kt) {
                bf16x8 a;
#pragma unroll
                for (int e = 0; e < 8; ++e)
                    a[e] = (short)f2bf(wsrc[g][(3 + kt * 32 + l16 * 8 + e) * H_SZ + c]);
                wA[kt][ct][g] = a;
            }
    }

    // static input gate (bf16-packed) + cell state
    unsigned int ivp[2][2];
    float cst[2][4];
    {
        const float xs0 = x_stat[(rb + m) * 3 + 0];
        const float xs1 = x_stat[(rb + m) * 3 + 1];
        const float xs2 = x_stat[(rb + m) * 3 + 2];
#pragma unroll
        for (int ct = 0; ct < 2; ++ct) {
            float ivq[4];
#pragma unroll
            for (int q = 0; q < 4; ++q) {
                const int c = wbase + ct * 16 + l16 * 4 + q;
                ivq[q] = fast_sigmoid(b_i[c] + xs0 * w_i[c] + xs1 * w_i[H_SZ + c]
                                             + xs2 * w_i[2 * H_SZ + c]);
                cst[ct][q] = 0.0f;
            }
            ivp[ct][0] = (unsigned)f2bf(ivq[0]) | ((unsigned)f2bf(ivq[1]) << 16);
            ivp[ct][1] = (unsigned)f2bf(ivq[2]) | ((unsigned)f2bf(ivq[3]) << 16);
        }
    }

    // h-write offsets: c0 = wbase+ct*16+l16*4; kt=c0>>5; L=m+16*((c0&31)>>3); e=c0&7
    int woff[2];
#pragma unroll
    for (int ct = 0; ct < 2; ++ct) {
        const int c0 = wbase + ct * 16 + l16 * 4;
        woff[ct] = ((c0 >> 5) * 64 + m + 16 * ((c0 & 31) >> 3)) * 8 + (c0 & 7);
    }

    // x prefetch (fp32, per-row; broadcast across l16 groups via L1)
    const float* xrow = x_dyn + (size_t)(rb + m) * XLEN;
    float x0 = xrow[0], x1 = xrow[1], x2 = xrow[2];

    __syncthreads();

    for (int t = 0; t < T_STEPS; ++t) {
        const int cur = t & 1;

        // prefetch next step's x (issues early; used after the barrier)
        const int tn = (t + 1 < T_STEPS) ? t + 1 : t;
        const float nx0 = xrow[tn * 3 + 0];
        const float nx1 = xrow[tn * 3 + 1];
        const float nx2 = xrow[tn * 3 + 2];

        // acc init: z = x @ Wx + b (VALU; wxlds reads broadcast within 16 lanes)
        f32x4 acc[2][3];
#pragma unroll
        for (int ct = 0; ct < 2; ++ct) {
            const int c0 = wbase + ct * 16 + l16 * 4;
#pragma unroll
            for (int g = 0; g < 3; ++g)
#pragma unroll
                for (int q = 0; q < 4; ++q) {
                    const f32x4 w = wxlds[g][c0 + q];
                    acc[ct][g][q] = w[3] + x0 * w[0] + x1 * w[1] + x2 * w[2];
                }
        }

        // z += h @ Wh : f,g from registers; o-gate A-frags streamed from LDS
        const bf16x8* hp  = (const bf16x8*)hbuf[cur];
        const bf16x8* wop = (const bf16x8*)wo_lds;
#pragma unroll
        for (int kt = 0; kt < 8; ++kt) {
            const bf16x8 b   = hp[kt * 64 + lane];
            const bf16x8 wo0 = wop[(kt * 4 + l16) * 256 + wbase + m];
            const bf16x8 wo1 = wop[(kt * 4 + l16) * 256 + wbase + 16 + m];
            acc[0][0] = __builtin_amdgcn_mfma_f32_16x16x32_bf16(wA[kt][0][0], b, acc[0][0], 0, 0, 0);
            acc[0][1] = __builtin_amdgcn_mfma_f32_16x16x32_bf16(wA[kt][0][1], b, acc[0][1], 0, 0, 0);
            acc[1][0] = __builtin_amdgcn_mfma_f32_16x16x32_bf16(wA[kt][1][0], b, acc[1][0], 0, 0, 0);
            acc[1][1] = __builtin_amdgcn_mfma_f32_16x16x32_bf16(wA[kt][1][1], b, acc[1][1], 0, 0, 0);
            acc[0][2] = __builtin_amdgcn_mfma_f32_16x16x32_bf16(wo0,         b, acc[0][2], 0, 0, 0);
            acc[1][2] = __builtin_amdgcn_mfma_f32_16x16x32_bf16(wo1,         b, acc[1][2], 0, 0, 0);
        }

        // gates + state; h -> LDS (b64 contiguous); always write (head reads back)
        unsigned short* hw = hbuf[cur ^ 1];
#pragma unroll
        for (int ct = 0; ct < 2; ++ct) {
            const float ivq[4] = {
                __uint_as_float(ivp[ct][0] << 16),
                __uint_as_float(ivp[ct][0] & 0xffff0000u),
                __uint_as_float(ivp[ct][1] << 16),
                __uint_as_float(ivp[ct][1] & 0xffff0000u)};
            bf16x4 pk;
#pragma unroll
            for (int q = 0; q < 4; ++q) {
                const float fq = fast_sigmoid(acc[ct][0][q]);
                const float gq = fast_tanh(acc[ct][1][q]);
                const float oq = fast_sigmoid(acc[ct][2][q]);
                const float cq = fq * cst[ct][q] + ivq[q] * gq;
                cst[ct][q] = cq;
                pk[q] = (short)f2bf(oq * fast_tanh(cq));
            }
            *(bf16x4*)&hw[woff[ct]] = pk;
        }
        x0 = nx0; x1 = nx1; x2 = nx2;
        __syncthreads();
    }

    // ---- head: out[r] = sum_c h[r][c] w_head[c] + b_head ----
    float p = 0.0f;
    const unsigned short* hf = hbuf[1];   // t=364 wrote buf (364&1)^1 = 1
#pragma unroll
    for (int ct = 0; ct < 2; ++ct) {
        const int c0 = wbase + ct * 16 + l16 * 4;
        const f32x4 wh = *(const f32x4*)&w_head[c0];
        const bf16x4 hv = *(const bf16x4*)&hf[woff[ct]];
#pragma unroll
        for (int q = 0; q < 4; ++q) p += bf2f((unsigned short)hv[q]) * wh[q];
    }
    p += __shfl_xor(p, 16);
    p += __shfl_xor(p, 32);
    if (lane < 16) red[wv][m] = p;
    __syncthreads();
    if (tid < ROWS) {
        float s = b_head[0];
#pragma unroll
        for (int w = 0; w < NW; ++w) s += red[w][tid];
        out[rb + tid] = s;
    }
}

extern "C" void kernel_launch(void* const* d_in, const int* in_sizes, int n_in,
                              void* d_out, int out_size, void* d_ws, size_t ws_size,
                              hipStream_t stream)
{
    const float* x_dyn  = (const float*)d_in[0];
    const float* x_stat = (const float*)d_in[1];
    const float* w_i    = (const float*)d_in[2];
    const float* b_i    = (const float*)d_in[3];
    const float* w_f    = (const float*)d_in[4];
    const float* b_f    = (const float*)d_in[5];
    const float* w_g    = (const float*)d_in[6];
    const float* b_g    = (const float*)d_in[7];
    const float* w_o    = (const float*)d_in[8];
    const float* b_o    = (const float*)d_in[9];
    const float* w_head = (const float*)d_in[10];
    const float* b_head = (const float*)d_in[11];

    ealstm_fused<<<dim3(64), dim3(512), 0, stream>>>(
        x_dyn, x_stat, w_i, b_i, w_f, b_f, w_g, b_g, w_o, b_o,
        w_head, b_head, (float*)d_out);
}

// Round 8
// 807.131 us; speedup vs baseline: 2.2811x; 1.0257x over previous
//
#include <hip/hip_runtime.h>

#define T_STEPS 365
#define XLEN    (T_STEPS * 3)
#define H_SZ    256
#define ROWS    16
#define NW      8      // waves per block (2 per SIMD -> 256-reg budget)
#define CPW     32     // state cols per wave
#define KTR     3      // o-gate k-tiles held in registers
#define KTL     (8 - KTR)

typedef __attribute__((ext_vector_type(8))) short bf16x8;   // 8 bf16 = 4 VGPRs
typedef __attribute__((ext_vector_type(4))) short bf16x4;   // 4 bf16 = 2 VGPRs
typedef __attribute__((ext_vector_type(4))) float f32x4;

__device__ __forceinline__ float fast_sigmoid(float x) {
    return __builtin_amdgcn_rcpf(1.0f + __builtin_amdgcn_exp2f(-1.44269504f * x));
}
__device__ __forceinline__ float fast_tanh(float x) {
    return 2.0f * __builtin_amdgcn_rcpf(1.0f + __builtin_amdgcn_exp2f(-2.88539008f * x)) - 1.0f;
}
__device__ __forceinline__ unsigned short f2bf(float x) {   // fp32 -> bf16 RTNE
    unsigned int u = __float_as_uint(x);
    u = (u + 0x7FFFu + ((u >> 16) & 1u)) >> 16;
    return (unsigned short)u;
}
__device__ __forceinline__ float bf2f(unsigned short v) {
    return __uint_as_float(((unsigned)v) << 16);
}
__device__ __forceinline__ bf16x8 expand4(bf16x4 v) {       // {v0..v3,0,0,0,0}
    bf16x8 r = (bf16x8)0;
    r[0] = v[0]; r[1] = v[1]; r[2] = v[2]; r[3] = v[3];
    return r;
}

// One block = 8 waves = 16 batch rows x all 256 state cols; wave owns 32 cols.
// Transposed MFMA (proven maps): D[c][r] = sum_k W^T[c][k] hx^T[k][r].
// LDS-issue engineering (round-7 lesson: 12 cyc per ds_read_b128 per wave,
// broadcast doesn't help): 48 -> ~21 LDS instr/wave/step.
//   regs: wA f,g (128) + wOr o-gate kt<3 (24) + wX x-tile (12) + acc 24 + misc
//   LDS : o-gate kt3..7 A-frags (80 KB), xpack (45.6 KB), hbuf dbuf (16 KB).
// x/bias folded into MFMA as K=32 tile (round-6-proven expand4 path).
__global__ void __launch_bounds__(512, 2)
ealstm_fused(const float* __restrict__ x_dyn, const float* __restrict__ x_stat,
             const float* __restrict__ w_i, const float* __restrict__ b_i,
             const float* __restrict__ w_f, const float* __restrict__ b_f,
             const float* __restrict__ w_g, const float* __restrict__ b_g,
             const float* __restrict__ w_o, const float* __restrict__ b_o,
             const float* __restrict__ w_head, const float* __restrict__ b_head,
             float* __restrict__ out)
{
    const int tid   = threadIdx.x;
    const int lane  = tid & 63;
    const int wv    = tid >> 6;       // 0..7
    const int m     = lane & 15;      // batch row (N dim of D)
    const int l16   = lane >> 4;      // 0..3
    const int rb    = blockIdx.x * ROWS;
    const int wbase = wv * CPW;

    __shared__ unsigned short wo_lds[KTL * 4 * 256 * 8];  // 80 KB [kt][l16][c][e]
    __shared__ unsigned short hbuf[2][4096];              // 16 KB h^T B-pack, dbuf
    __shared__ unsigned short xpack[T_STEPS][64];         // 45.6 KB {x0,x1,x2,1} bf16
    __shared__ float          red[NW][ROWS];

    const float* wsrc[3] = {w_f, w_g, w_o};
    const float* bsrc[3] = {b_f, b_g, b_o};

    // ---- one-time staging ----
    for (int idx = tid; idx < T_STEPS * ROWS; idx += 512) {
        const int t = idx % T_STEPS, r = idx / T_STEPS;
        const float* s = x_dyn + (size_t)(rb + r) * XLEN + t * 3;
        bf16x4 pk;
        pk[0] = (short)f2bf(s[0]); pk[1] = (short)f2bf(s[1]);
        pk[2] = (short)f2bf(s[2]); pk[3] = (short)0x3F80;      // 1.0 bf16
        *(bf16x4*)&xpack[t][r * 4] = pk;
    }
    // o-gate Wh kt=KTR..7 -> LDS A-frags
    for (int idx = tid; idx < KTL * 4 * 8 * 256; idx += 512) {
        const int c    = idx & 255;
        const int e    = (idx >> 8) & 7;
        const int l16g = (idx >> 11) & 3;
        const int kt   = idx >> 13;                            // 0..KTL-1
        wo_lds[((kt * 4 + l16g) * 256 + c) * 8 + e] =
            f2bf(w_o[(3 + (kt + KTR) * 32 + l16g * 8 + e) * H_SZ + c]);
    }
    for (int idx = tid; idx < 2048; idx += 512) ((unsigned int*)hbuf[0])[idx] = 0u;

    // ---- weights -> registers ----
    // A map (K=32): lane holds A[c = wbase+ct*16+(lane&15)][k' = l16*8+e]
    bf16x8 wA[8][2][2];      // f,g gates, all 8 kt (128 regs)
    bf16x8 wOr[KTR][2];      // o gate, kt < KTR (24 regs)
    bf16x4 wX[2][3];         // x/bias tile (12 regs); nonzero only l16==0
#pragma unroll
    for (int ct = 0; ct < 2; ++ct) {
        const int c = wbase + ct * 16 + m;
#pragma unroll
        for (int g = 0; g < 2; ++g)
#pragma unroll
            for (int kt = 0; kt < 8; ++kt) {
                bf16x8 a;
#pragma unroll
                for (int e = 0; e < 8; ++e)
                    a[e] = (short)f2bf(wsrc[g][(3 + kt * 32 + l16 * 8 + e) * H_SZ + c]);
                wA[kt][ct][g] = a;
            }
#pragma unroll
        for (int kt = 0; kt < KTR; ++kt) {
            bf16x8 a;
#pragma unroll
            for (int e = 0; e < 8; ++e)
                a[e] = (short)f2bf(w_o[(3 + kt * 32 + l16 * 8 + e) * H_SZ + c]);
            wOr[kt][ct] = a;
        }
#pragma unroll
        for (int g = 0; g < 3; ++g) {
            bf16x4 ax = (bf16x4)0;
            if (l16 == 0) {
                ax[0] = (short)f2bf(wsrc[g][0 * H_SZ + c]);
                ax[1] = (short)f2bf(wsrc[g][1 * H_SZ + c]);
                ax[2] = (short)f2bf(wsrc[g][2 * H_SZ + c]);
                ax[3] = (short)f2bf(bsrc[g][c]);
            }
            wX[ct][g] = ax;
        }
    }

    // ---- static input gate (bf16-packed) + cell state ----
    unsigned int ivp[2][2];
    float cst[2][4];
    {
        const float xs0 = x_stat[(rb + m) * 3 + 0];
        const float xs1 = x_stat[(rb + m) * 3 + 1];
        const float xs2 = x_stat[(rb + m) * 3 + 2];
#pragma unroll
        for (int ct = 0; ct < 2; ++ct) {
            float ivq[4];
#pragma unroll
            for (int q = 0; q < 4; ++q) {
                const int c = wbase + ct * 16 + l16 * 4 + q;
                ivq[q] = fast_sigmoid(b_i[c] + xs0 * w_i[c] + xs1 * w_i[H_SZ + c]
                                             + xs2 * w_i[2 * H_SZ + c]);
                cst[ct][q] = 0.0f;
            }
            ivp[ct][0] = (unsigned)f2bf(ivq[0]) | ((unsigned)f2bf(ivq[1]) << 16);
            ivp[ct][1] = (unsigned)f2bf(ivq[2]) | ((unsigned)f2bf(ivq[3]) << 16);
        }
    }

    // h-write offsets: c0 = wbase+ct*16+l16*4; kt=c0>>5; L=m+16*((c0&31)>>3); e=c0&7
    int woff[2];
#pragma unroll
    for (int ct = 0; ct < 2; ++ct) {
        const int c0 = wbase + ct * 16 + l16 * 4;
        woff[ct] = ((c0 >> 5) * 64 + m + 16 * ((c0 & 31) >> 3)) * 8 + (c0 & 7);
    }

    __syncthreads();

    for (int t = 0; t < T_STEPS; ++t) {
        const int cur = t & 1;

        // x B-frag (K=32): lane holds B[k'=l16*8+e][r=m]; nonzero only l16==0,e<4
        bf16x8 xf = (bf16x8)0;
        {
            const bf16x4 v = *(const bf16x4*)&xpack[t][m * 4];
            if (l16 == 0) { xf[0] = v[0]; xf[1] = v[1]; xf[2] = v[2]; xf[3] = v[3]; }
        }

        // acc init via x-tile MFMA (expand wX transiently)
        f32x4 acc[2][3];
        {
            const f32x4 z4 = {0.f, 0.f, 0.f, 0.f};
#pragma unroll
            for (int ct = 0; ct < 2; ++ct)
#pragma unroll
                for (int g = 0; g < 3; ++g)
                    acc[ct][g] = __builtin_amdgcn_mfma_f32_16x16x32_bf16(
                        expand4(wX[ct][g]), xf, z4, 0, 0, 0);
        }

        // z += h @ Wh : f,g + o(kt<KTR) from regs; o(kt>=KTR) streamed from LDS
        const bf16x8* hp  = (const bf16x8*)hbuf[cur];
        const bf16x8* wop = (const bf16x8*)wo_lds;
#pragma unroll
        for (int kt = 0; kt < 8; ++kt) {
            const bf16x8 b = hp[kt * 64 + lane];
            bf16x8 wo0, wo1;
            if (kt < KTR) {
                wo0 = wOr[kt][0];
                wo1 = wOr[kt][1];
            } else {
                wo0 = wop[((kt - KTR) * 4 + l16) * 256 + wbase + m];
                wo1 = wop[((kt - KTR) * 4 + l16) * 256 + wbase + 16 + m];
            }
            acc[0][0] = __builtin_amdgcn_mfma_f32_16x16x32_bf16(wA[kt][0][0], b, acc[0][0], 0, 0, 0);
            acc[0][1] = __builtin_amdgcn_mfma_f32_16x16x32_bf16(wA[kt][0][1], b, acc[0][1], 0, 0, 0);
            acc[1][0] = __builtin_amdgcn_mfma_f32_16x16x32_bf16(wA[kt][1][0], b, acc[1][0], 0, 0, 0);
            acc[1][1] = __builtin_amdgcn_mfma_f32_16x16x32_bf16(wA[kt][1][1], b, acc[1][1], 0, 0, 0);
            acc[0][2] = __builtin_amdgcn_mfma_f32_16x16x32_bf16(wo0,          b, acc[0][2], 0, 0, 0);
            acc[1][2] = __builtin_amdgcn_mfma_f32_16x16x32_bf16(wo1,          b, acc[1][2], 0, 0, 0);
        }

        // gates + state; h -> LDS (b64 contiguous); always write (head reads back)
        unsigned short* hw = hbuf[cur ^ 1];
#pragma unroll
        for (int ct = 0; ct < 2; ++ct) {
            const float ivq[4] = {
                __uint_as_float(ivp[ct][0] << 16),
                __uint_as_float(ivp[ct][0] & 0xffff0000u),
                __uint_as_float(ivp[ct][1] << 16),
                __uint_as_float(ivp[ct][1] & 0xffff0000u)};
            bf16x4 pk;
#pragma unroll
            for (int q = 0; q < 4; ++q) {
                const float fq = fast_sigmoid(acc[ct][0][q]);
                const float gq = fast_tanh(acc[ct][1][q]);
                const float oq = fast_sigmoid(acc[ct][2][q]);
                const float cq = fq * cst[ct][q] + ivq[q] * gq;
                cst[ct][q] = cq;
                pk[q] = (short)f2bf(oq * fast_tanh(cq));
            }
            *(bf16x4*)&hw[woff[ct]] = pk;
        }
        __syncthreads();
    }

    // ---- head: out[r] = sum_c h[r][c] w_head[c] + b_head ----
    float p = 0.0f;
    const unsigned short* hf = hbuf[1];   // t=364 wrote buf (364&1)^1 = 1
#pragma unroll
    for (int ct = 0; ct < 2; ++ct) {
        const int c0 = wbase + ct * 16 + l16 * 4;
        const f32x4 wh = *(const f32x4*)&w_head[c0];
        const bf16x4 hv = *(const bf16x4*)&hf[woff[ct]];
#pragma unroll
        for (int q = 0; q < 4; ++q) p += bf2f((unsigned short)hv[q]) * wh[q];
    }
    p += __shfl_xor(p, 16);
    p += __shfl_xor(p, 32);
    if (lane < 16) red[wv][m] = p;
    __syncthreads();
    if (tid < ROWS) {
        float s = b_head[0];
#pragma unroll
        for (int w = 0; w < NW; ++w) s += red[w][tid];
        out[rb + tid] = s;
    }
}

extern "C" void kernel_launch(void* const* d_in, const int* in_sizes, int n_in,
                              void* d_out, int out_size, void* d_ws, size_t ws_size,
                              hipStream_t stream)
{
    const float* x_dyn  = (const float*)d_in[0];
    const float* x_stat = (const float*)d_in[1];
    const float* w_i    = (const float*)d_in[2];
    const float* b_i    = (const float*)d_in[3];
    const float* w_f    = (const float*)d_in[4];
    const float* b_f    = (const float*)d_in[5];
    const float* w_g    = (const float*)d_in[6];
    const float* b_g    = (const float*)d_in[7];
    const float* w_o    = (const float*)d_in[8];
    const float* b_o    = (const float*)d_in[9];
    const float* w_head = (const float*)d_in[10];
    const float* b_head = (const float*)d_in[11];

    ealstm_fused<<<dim3(64), dim3(512), 0, stream>>>(
        x_dyn, x_stat, w_i, b_i, w_f, b_f, w_g, b_g, w_o, b_o,
        w_head, b_head, (float*)d_out);
}

// Round 9
// 666.797 us; speedup vs baseline: 2.7611x; 1.2105x over previous
//
#include <hip/hip_runtime.h>

#define T_STEPS 365
#define XLEN    (T_STEPS * 3)
#define H_SZ    256
#define ROWS    16
#define NW      8      // waves per block (2 per SIMD)
#define CPW     32     // state cols per wave
#define KTR     3      // o-gate k-tiles held in registers
#define KTL     (8 - KTR)

typedef __attribute__((ext_vector_type(8))) short bf16x8;   // 8 bf16 = 4 VGPRs
typedef __attribute__((ext_vector_type(4))) short bf16x4;   // 4 bf16 = 2 VGPRs
typedef __attribute__((ext_vector_type(4))) float f32x4;

__device__ __forceinline__ float fast_sigmoid(float x) {
    return __builtin_amdgcn_rcpf(1.0f + __builtin_amdgcn_exp2f(-1.44269504f * x));
}
__device__ __forceinline__ float fast_tanh(float x) {
    return 2.0f * __builtin_amdgcn_rcpf(1.0f + __builtin_amdgcn_exp2f(-2.88539008f * x)) - 1.0f;
}
__device__ __forceinline__ unsigned short f2bf(float x) {   // fp32 -> bf16 RTNE
    unsigned int u = __float_as_uint(x);
    u = (u + 0x7FFFu + ((u >> 16) & 1u)) >> 16;
    return (unsigned short)u;
}
__device__ __forceinline__ float bf2f(unsigned short v) {
    return __uint_as_float(((unsigned)v) << 16);
}
__device__ __forceinline__ bf16x8 expand4(bf16x4 v) {       // {v0..v3,0,0,0,0}
    bf16x8 r = (bf16x8)0;
    r[0] = v[0]; r[1] = v[1]; r[2] = v[2]; r[3] = v[3];
    return r;
}

// One block = 8 waves = 16 batch rows x all 256 state cols; wave owns 32 cols.
// Transposed MFMA (proven maps): D[c][r] = sum_k W^T[c][k] hx^T[k][r].
// Round-9 restructure (round-8 lesson: phases serialize, sum not max):
//   * ct-MAJOR MFMA order: acc chains for ct0 finish early -> gates(ct0)
//     overlap ct1's MFMA stream (scheduler-visible independence).
//   * all 8 h B-frags prefetched to regs (1 latency wait, reused by both ct).
//   * x-tile A-frags demoted to compact 6 KB LDS table (frees 24 regs).
// Census: wA 128 + wOr 24 + acc 24 + hb 32 + temps ~30 < 256.
__global__ void __launch_bounds__(512, 2)
ealstm_fused(const float* __restrict__ x_dyn, const float* __restrict__ x_stat,
             const float* __restrict__ w_i, const float* __restrict__ b_i,
             const float* __restrict__ w_f, const float* __restrict__ b_f,
             const float* __restrict__ w_g, const float* __restrict__ b_g,
             const float* __restrict__ w_o, const float* __restrict__ b_o,
             const float* __restrict__ w_head, const float* __restrict__ b_head,
             float* __restrict__ out)
{
    const int tid   = threadIdx.x;
    const int lane  = tid & 63;
    const int wv    = tid >> 6;       // 0..7
    const int m     = lane & 15;      // batch row (N dim of D)
    const int l16   = lane >> 4;      // 0..3
    const int rb    = blockIdx.x * ROWS;
    const int wbase = wv * CPW;

    __shared__ unsigned short wo_lds[KTL * 4 * 256 * 8];  // 80 KB [kt][l16][c][e]
    __shared__ unsigned short hbuf[2][4096];              // 16 KB h^T B-pack, dbuf
    __shared__ unsigned short xpack[T_STEPS][64];         // 45.6 KB {x0,x1,x2,1} bf16
    __shared__ uint4          wxc4[3 * 8 * 16];           // 6 KB x-tile A-frags
    __shared__ float          red[NW][ROWS];

    const float* wsrc[3] = {w_f, w_g, w_o};
    const float* bsrc[3] = {b_f, b_g, b_o};

    // ---- one-time staging ----
    for (int idx = tid; idx < T_STEPS * ROWS; idx += 512) {
        const int t = idx % T_STEPS, r = idx / T_STEPS;
        const float* s = x_dyn + (size_t)(rb + r) * XLEN + t * 3;
        bf16x4 pk;
        pk[0] = (short)f2bf(s[0]); pk[1] = (short)f2bf(s[1]);
        pk[2] = (short)f2bf(s[2]); pk[3] = (short)0x3F80;      // 1.0 bf16
        *(bf16x4*)&xpack[t][r * 4] = pk;
    }
    // o-gate Wh kt=KTR..7 -> LDS A-frags
    for (int idx = tid; idx < KTL * 4 * 8 * 256; idx += 512) {
        const int c    = idx & 255;
        const int e    = (idx >> 8) & 7;
        const int l16g = (idx >> 11) & 3;
        const int kt   = idx >> 13;                            // 0..KTL-1
        wo_lds[((kt * 4 + l16g) * 256 + c) * 8 + e] =
            f2bf(w_o[(3 + (kt + KTR) * 32 + l16g * 8 + e) * H_SZ + c]);
    }
    // x-tile coef table: wxc[g][wvb][m] = {ct0:{w0,w1,w2,b}, ct1:{w0,w1,w2,b}}
    for (int idx = tid; idx < 3 * 8 * 16 * 8; idx += 512) {
        const int e   = idx & 3;
        const int ct  = (idx >> 2) & 1;
        const int mm  = (idx >> 3) & 15;
        const int wvb = (idx >> 7) & 7;
        const int g   = idx >> 10;
        const int c   = wvb * 32 + ct * 16 + mm;
        ((unsigned short*)wxc4)[((g * 8 + wvb) * 16 + mm) * 8 + ct * 4 + e] =
            f2bf(e < 3 ? wsrc[g][e * H_SZ + c] : bsrc[g][c]);
    }
    for (int idx = tid; idx < 2048; idx += 512) ((unsigned int*)hbuf[0])[idx] = 0u;

    // ---- weights -> registers ----
    // A map (K=32): lane holds A[c = wbase+ct*16+(lane&15)][k' = l16*8+e]
    bf16x8 wA[8][2][2];      // f,g gates, all 8 kt (128 regs)
    bf16x8 wOr[KTR][2];      // o gate, kt < KTR (24 regs)
#pragma unroll
    for (int ct = 0; ct < 2; ++ct) {
        const int c = wbase + ct * 16 + m;
#pragma unroll
        for (int g = 0; g < 2; ++g)
#pragma unroll
            for (int kt = 0; kt < 8; ++kt) {
                bf16x8 a;
#pragma unroll
                for (int e = 0; e < 8; ++e)
                    a[e] = (short)f2bf(wsrc[g][(3 + kt * 32 + l16 * 8 + e) * H_SZ + c]);
                wA[kt][ct][g] = a;
            }
#pragma unroll
        for (int kt = 0; kt < KTR; ++kt) {
            bf16x8 a;
#pragma unroll
            for (int e = 0; e < 8; ++e)
                a[e] = (short)f2bf(w_o[(3 + kt * 32 + l16 * 8 + e) * H_SZ + c]);
            wOr[kt][ct] = a;
        }
    }

    // ---- static input gate (bf16-packed) + cell state ----
    unsigned int ivp[2][2];
    float cst[2][4];
    {
        const float xs0 = x_stat[(rb + m) * 3 + 0];
        const float xs1 = x_stat[(rb + m) * 3 + 1];
        const float xs2 = x_stat[(rb + m) * 3 + 2];
#pragma unroll
        for (int ct = 0; ct < 2; ++ct) {
            float ivq[4];
#pragma unroll
            for (int q = 0; q < 4; ++q) {
                const int c = wbase + ct * 16 + l16 * 4 + q;
                ivq[q] = fast_sigmoid(b_i[c] + xs0 * w_i[c] + xs1 * w_i[H_SZ + c]
                                             + xs2 * w_i[2 * H_SZ + c]);
                cst[ct][q] = 0.0f;
            }
            ivp[ct][0] = (unsigned)f2bf(ivq[0]) | ((unsigned)f2bf(ivq[1]) << 16);
            ivp[ct][1] = (unsigned)f2bf(ivq[2]) | ((unsigned)f2bf(ivq[3]) << 16);
        }
    }

    // h-write offsets: c0 = wbase+ct*16+l16*4; kt=c0>>5; L=m+16*((c0&31)>>3); e=c0&7
    int woff[2];
#pragma unroll
    for (int ct = 0; ct < 2; ++ct) {
        const int c0 = wbase + ct * 16 + l16 * 4;
        woff[ct] = ((c0 >> 5) * 64 + m + 16 * ((c0 & 31) >> 3)) * 8 + (c0 & 7);
    }

    __syncthreads();

    for (int t = 0; t < T_STEPS; ++t) {
        const int cur = t & 1;
        const bf16x8* hp  = (const bf16x8*)hbuf[cur];
        const bf16x8* wop = (const bf16x8*)wo_lds;
        unsigned short* hw = hbuf[cur ^ 1];

        // ---- reads up front: x frags + all 8 h B-frags (one latency wait) ----
        bf16x8 xf = (bf16x8)0;
        {
            const bf16x4 v = *(const bf16x4*)&xpack[t][m * 4];
            if (l16 == 0) { xf[0] = v[0]; xf[1] = v[1]; xf[2] = v[2]; xf[3] = v[3]; }
        }
        bf16x4 xa[2][3];    // x-tile A-frags (lo/hi halves of one b128 per gate)
#pragma unroll
        for (int g = 0; g < 3; ++g) {
            uint4 w4 = wxc4[(g * 8 + wv) * 16 + m];
            if (l16 != 0) { w4.x = 0; w4.y = 0; w4.z = 0; w4.w = 0; }
            xa[0][g] = *(bf16x4*)&w4.x;
            xa[1][g] = *(bf16x4*)&w4.z;
        }
        bf16x8 hb[8];
#pragma unroll
        for (int kt = 0; kt < 8; ++kt) hb[kt] = hp[kt * 64 + lane];

        f32x4 acc[2][3];
        const f32x4 z4 = {0.f, 0.f, 0.f, 0.f};

        // ================= ct = 0: 27 MFMAs, then gates (overlaps ct1) =======
#pragma unroll
        for (int g = 0; g < 3; ++g)
            acc[0][g] = __builtin_amdgcn_mfma_f32_16x16x32_bf16(
                expand4(xa[0][g]), xf, z4, 0, 0, 0);
#pragma unroll
        for (int kt = 0; kt < 8; ++kt) {
            const bf16x8 wo0 = (kt < KTR)
                ? wOr[kt][0]
                : wop[((kt - KTR) * 4 + l16) * 256 + wbase + m];
            acc[0][0] = __builtin_amdgcn_mfma_f32_16x16x32_bf16(wA[kt][0][0], hb[kt], acc[0][0], 0, 0, 0);
            acc[0][1] = __builtin_amdgcn_mfma_f32_16x16x32_bf16(wA[kt][0][1], hb[kt], acc[0][1], 0, 0, 0);
            acc[0][2] = __builtin_amdgcn_mfma_f32_16x16x32_bf16(wo0,          hb[kt], acc[0][2], 0, 0, 0);
        }
        {   // gates ct0 + early h-write (independent of ct1 MFMA stream)
            const float ivq[4] = {
                __uint_as_float(ivp[0][0] << 16),
                __uint_as_float(ivp[0][0] & 0xffff0000u),
                __uint_as_float(ivp[0][1] << 16),
                __uint_as_float(ivp[0][1] & 0xffff0000u)};
            bf16x4 pk;
#pragma unroll
            for (int q = 0; q < 4; ++q) {
                const float fq = fast_sigmoid(acc[0][0][q]);
                const float gq = fast_tanh(acc[0][1][q]);
                const float oq = fast_sigmoid(acc[0][2][q]);
                const float cq = fq * cst[0][q] + ivq[q] * gq;
                cst[0][q] = cq;
                pk[q] = (short)f2bf(oq * fast_tanh(cq));
            }
            *(bf16x4*)&hw[woff[0]] = pk;
        }

        // ================= ct = 1: 27 MFMAs, then gates ======================
#pragma unroll
        for (int g = 0; g < 3; ++g)
            acc[1][g] = __builtin_amdgcn_mfma_f32_16x16x32_bf16(
                expand4(xa[1][g]), xf, z4, 0, 0, 0);
#pragma unroll
        for (int kt = 0; kt < 8; ++kt) {
            const bf16x8 wo1 = (kt < KTR)
                ? wOr[kt][1]
                : wop[((kt - KTR) * 4 + l16) * 256 + wbase + 16 + m];
            acc[1][0] = __builtin_amdgcn_mfma_f32_16x16x32_bf16(wA[kt][1][0], hb[kt], acc[1][0], 0, 0, 0);
            acc[1][1] = __builtin_amdgcn_mfma_f32_16x16x32_bf16(wA[kt][1][1], hb[kt], acc[1][1], 0, 0, 0);
            acc[1][2] = __builtin_amdgcn_mfma_f32_16x16x32_bf16(wo1,          hb[kt], acc[1][2], 0, 0, 0);
        }
        {
            const float ivq[4] = {
                __uint_as_float(ivp[1][0] << 16),
                __uint_as_float(ivp[1][0] & 0xffff0000u),
                __uint_as_float(ivp[1][1] << 16),
                __uint_as_float(ivp[1][1] & 0xffff0000u)};
            bf16x4 pk;
#pragma unroll
            for (int q = 0; q < 4; ++q) {
                const float fq = fast_sigmoid(acc[1][0][q]);
                const float gq = fast_tanh(acc[1][1][q]);
                const float oq = fast_sigmoid(acc[1][2][q]);
                const float cq = fq * cst[1][q] + ivq[q] * gq;
                cst[1][q] = cq;
                pk[q] = (short)f2bf(oq * fast_tanh(cq));
            }
            *(bf16x4*)&hw[woff[1]] = pk;
        }
        __syncthreads();
    }

    // ---- head: out[r] = sum_c h[r][c] w_head[c] + b_head ----
    float p = 0.0f;
    const unsigned short* hf = hbuf[1];   // t=364 wrote buf (364&1)^1 = 1
#pragma unroll
    for (int ct = 0; ct < 2; ++ct) {
        const int c0 = wbase + ct * 16 + l16 * 4;
        const f32x4 wh = *(const f32x4*)&w_head[c0];
        const bf16x4 hv = *(const bf16x4*)&hf[woff[ct]];
#pragma unroll
        for (int q = 0; q < 4; ++q) p += bf2f((unsigned short)hv[q]) * wh[q];
    }
    p += __shfl_xor(p, 16);
    p += __shfl_xor(p, 32);
    if (lane < 16) red[wv][m] = p;
    __syncthreads();
    if (tid < ROWS) {
        float s = b_head[0];
#pragma unroll
        for (int w = 0; w < NW; ++w) s += red[w][tid];
        out[rb + tid] = s;
    }
}

extern "C" void kernel_launch(void* const* d_in, const int* in_sizes, int n_in,
                              void* d_out, int out_size, void* d_ws, size_t ws_size,
                              hipStream_t stream)
{
    const float* x_dyn  = (const float*)d_in[0];
    const float* x_stat = (const float*)d_in[1];
    const float* w_i    = (const float*)d_in[2];
    const float* b_i    = (const float*)d_in[3];
    const float* w_f    = (const float*)d_in[4];
    const float* b_f    = (const float*)d_in[5];
    const float* w_g    = (const float*)d_in[6];
    const float* b_g    = (const float*)d_in[7];
    const float* w_o    = (const float*)d_in[8];
    const float* b_o    = (const float*)d_in[9];
    const float* w_head = (const float*)d_in[10];
    const float* b_head = (const float*)d_in[11];

    ealstm_fused<<<dim3(64), dim3(512), 0, stream>>>(
        x_dyn, x_stat, w_i, b_i, w_f, b_f, w_g, b_g, w_o, b_o,
        w_head, b_head, (float*)d_out);
}

// Round 10
// 569.100 us; speedup vs baseline: 3.2351x; 1.1717x over previous
//
#include <hip/hip_runtime.h>
#include <hip/hip_bf16.h>

#define T_STEPS 365
#define XLEN    (T_STEPS * 3)
#define H_SZ    256
#define ROWS    16
#define NW      8      // waves per block (2 per SIMD)
#define CPW     32     // state cols per wave

#define SF1     (-1.4426950408889634f)   // -log2(e): folded into W_f, W_o
#define SF2     (-2.8853900817779268f)   // -2 log2(e): folded into W_g, tanh(c)

typedef __attribute__((ext_vector_type(8))) short bf16x8;   // 8 bf16 = 4 VGPRs
typedef __attribute__((ext_vector_type(4))) short bf16x4;   // 4 bf16 = 2 VGPRs
typedef __attribute__((ext_vector_type(4))) float f32x4;

__device__ __forceinline__ float fast_sigmoid(float x) {    // plain form (iv only)
    return __builtin_amdgcn_rcpf(1.0f + __builtin_amdgcn_exp2f(-1.44269504f * x));
}
__device__ __forceinline__ unsigned short f2bf(float x) {   // fp32 -> bf16 RTNE
    __hip_bfloat16 b = __float2bfloat16(x);
    return *reinterpret_cast<unsigned short*>(&b);
}
__device__ __forceinline__ float bf2f(unsigned short v) {
    return __uint_as_float(((unsigned)v) << 16);
}
__device__ __forceinline__ bf16x8 expand4(bf16x4 v) {       // {v0..v3,0,0,0,0}
    bf16x8 r = (bf16x8)0;
    r[0] = v[0]; r[1] = v[1]; r[2] = v[2]; r[3] = v[3];
    return r;
}

// pre-kernel: pack x_dyn -> d_ws as bf16 {x0,x1,x2,1.0} per (block,t,row)
__global__ void __launch_bounds__(256)
xstage(const float* __restrict__ x_dyn, unsigned short* __restrict__ xg)
{
    const int rb = blockIdx.x * ROWS;
    for (int idx = threadIdx.x; idx < T_STEPS * ROWS; idx += 256) {
        const int t = idx % T_STEPS, r = idx / T_STEPS;
        const float* s = x_dyn + (size_t)(rb + r) * XLEN + t * 3;
        bf16x4 pk;
        pk[0] = (short)f2bf(s[0]); pk[1] = (short)f2bf(s[1]);
        pk[2] = (short)f2bf(s[2]); pk[3] = (short)0x3F80;   // 1.0 bf16
        *(bf16x4*)&xg[((size_t)blockIdx.x * T_STEPS + t) * 64 + r * 4] = pk;
    }
}

// One block = 8 waves = 16 batch rows x all 256 state cols; wave owns 32 cols.
// Transposed MFMA (proven maps): D[c][r] = sum_k W^T[c][k] hx^T[k][r].
// Round-10: pre-scaled weights (exp2-native gates), o-gate fully in LDS
// ([l16][kt][c][e] layout -> all reads base+imm-offset), x from d_ws global,
// wA = exactly 128 regs (AGPR side), VGPR side ~115 -> allocator slack.
__global__ void __launch_bounds__(512, 2)
ealstm_fused(const unsigned short* __restrict__ xg, const float* __restrict__ x_stat,
             const float* __restrict__ w_i, const float* __restrict__ b_i,
             const float* __restrict__ w_f, const float* __restrict__ b_f,
             const float* __restrict__ w_g, const float* __restrict__ b_g,
             const float* __restrict__ w_o, const float* __restrict__ b_o,
             const float* __restrict__ w_head, const float* __restrict__ b_head,
             float* __restrict__ out)
{
    const int tid   = threadIdx.x;
    const int lane  = tid & 63;
    const int wv    = tid >> 6;       // 0..7
    const int m     = lane & 15;      // batch row (N dim of D)
    const int l16   = lane >> 4;      // 0..3
    const int rb    = blockIdx.x * ROWS;
    const int wbase = wv * CPW;

    __shared__ unsigned short wo_lds[4 * 8 * 256 * 8];    // 128 KB [l16][kt][c][e]
    __shared__ unsigned short hbuf[2][4096];              // 16 KB h^T B-pack, dbuf
    __shared__ float          red[NW][ROWS];

    // ---- one-time staging ----
    // o-gate Wh -> LDS A-frags, pre-scaled by SF1
    for (int idx = tid; idx < 4 * 8 * 8 * 256; idx += 512) {
        const int c    = idx & 255;
        const int e    = (idx >> 8) & 7;
        const int kt   = (idx >> 11) & 7;
        const int l16g = idx >> 14;
        wo_lds[((l16g * 8 + kt) * 256 + c) * 8 + e] =
            f2bf(SF1 * w_o[(3 + kt * 32 + l16g * 8 + e) * H_SZ + c]);
    }
    for (int idx = tid; idx < 2048; idx += 512) ((unsigned int*)hbuf[0])[idx] = 0u;

    const float* wsrc[3] = {w_f, w_g, w_o};
    const float* bsrc[3] = {b_f, b_g, b_o};
    const float  gsf[3]  = {SF1, SF2, SF1};

    // ---- weights -> registers (pre-scaled) ----
    // A map (K=32): lane holds A[c = wbase+ct*16+(lane&15)][k' = l16*8+e]
    bf16x8 wA[8][2][2];      // f,g gates, all 8 kt = 128 regs (AGPR side)
    bf16x4 wX[2][3];         // x/bias tile, 12 regs; nonzero only l16==0
#pragma unroll
    for (int ct = 0; ct < 2; ++ct) {
        const int c = wbase + ct * 16 + m;
#pragma unroll
        for (int g = 0; g < 2; ++g)
#pragma unroll
            for (int kt = 0; kt < 8; ++kt) {
                bf16x8 a;
#pragma unroll
                for (int e = 0; e < 8; ++e)
                    a[e] = (short)f2bf(gsf[g] * wsrc[g][(3 + kt * 32 + l16 * 8 + e) * H_SZ + c]);
                wA[kt][ct][g] = a;
            }
#pragma unroll
        for (int g = 0; g < 3; ++g) {
            bf16x4 ax = (bf16x4)0;
            if (l16 == 0) {
                ax[0] = (short)f2bf(gsf[g] * wsrc[g][0 * H_SZ + c]);
                ax[1] = (short)f2bf(gsf[g] * wsrc[g][1 * H_SZ + c]);
                ax[2] = (short)f2bf(gsf[g] * wsrc[g][2 * H_SZ + c]);
                ax[3] = (short)f2bf(gsf[g] * bsrc[g][c]);
            }
            wX[ct][g] = ax;
        }
    }

    // ---- static input gate (fp32 regs) + cell state ----
    float iv[2][4], cst[2][4];
    {
        const float xs0 = x_stat[(rb + m) * 3 + 0];
        const float xs1 = x_stat[(rb + m) * 3 + 1];
        const float xs2 = x_stat[(rb + m) * 3 + 2];
#pragma unroll
        for (int ct = 0; ct < 2; ++ct)
#pragma unroll
            for (int q = 0; q < 4; ++q) {
                const int c = wbase + ct * 16 + l16 * 4 + q;
                iv[ct][q] = fast_sigmoid(b_i[c] + xs0 * w_i[c] + xs1 * w_i[H_SZ + c]
                                                + xs2 * w_i[2 * H_SZ + c]);
                cst[ct][q] = 0.0f;
            }
    }

    // h-write offsets: c0 = wbase+ct*16+l16*4; kt=c0>>5; L=m+16*((c0&31)>>3); e=c0&7
    int woff[2];
#pragma unroll
    for (int ct = 0; ct < 2; ++ct) {
        const int c0 = wbase + ct * 16 + l16 * 4;
        woff[ct] = ((c0 >> 5) * 64 + m + 16 * ((c0 & 31) >> 3)) * 8 + (c0 & 7);
    }

    // loop-invariant base pointers (per-step reads fold into imm offsets)
    const unsigned short* xrow   = xg + (size_t)blockIdx.x * T_STEPS * 64 + m * 4;
    const bf16x8*         wobase = (const bf16x8*)&wo_lds[((l16 * 8) * 256 + wbase + m) * 8];

    __syncthreads();

    for (int t = 0; t < T_STEPS; ++t) {
        const int cur = t & 1;
        const bf16x8* hp = (const bf16x8*)hbuf[cur] + lane;
        unsigned short* hw = hbuf[cur ^ 1];

        // ---- all reads up front ----
        bf16x8 xf = (bf16x8)0;
        {
            unsigned long long xv = *(const unsigned long long*)&xrow[(size_t)t * 64];
            if (l16 != 0) xv = 0ULL;
            union { unsigned long long u; bf16x4 v; } X; X.u = xv;
            xf[0] = X.v[0]; xf[1] = X.v[1]; xf[2] = X.v[2]; xf[3] = X.v[3];
        }
        bf16x8 hb[8];
#pragma unroll
        for (int kt = 0; kt < 8; ++kt) hb[kt] = hp[kt * 64];

        f32x4 acc[2][3];
        const f32x4 z4 = {0.f, 0.f, 0.f, 0.f};

        // ================= ct = 0: x-tile + 24 MFMAs, then gates =============
#pragma unroll
        for (int g = 0; g < 3; ++g)
            acc[0][g] = __builtin_amdgcn_mfma_f32_16x16x32_bf16(
                expand4(wX[0][g]), xf, z4, 0, 0, 0);
#pragma unroll
        for (int kt = 0; kt < 8; ++kt) {
            const bf16x8 wo0 = wobase[kt * 256];                 // imm kt*4096
            acc[0][0] = __builtin_amdgcn_mfma_f32_16x16x32_bf16(wA[kt][0][0], hb[kt], acc[0][0], 0, 0, 0);
            acc[0][1] = __builtin_amdgcn_mfma_f32_16x16x32_bf16(wA[kt][0][1], hb[kt], acc[0][1], 0, 0, 0);
            acc[0][2] = __builtin_amdgcn_mfma_f32_16x16x32_bf16(wo0,          hb[kt], acc[0][2], 0, 0, 0);
        }
        {   // gates ct0 (exp2-native) + early h-write (overlaps ct1 MFMAs)
            bf16x4 pk;
#pragma unroll
            for (int q = 0; q < 4; ++q) {
                const float fq = __builtin_amdgcn_rcpf(1.0f + __builtin_amdgcn_exp2f(acc[0][0][q]));
                const float gq = 2.0f * __builtin_amdgcn_rcpf(1.0f + __builtin_amdgcn_exp2f(acc[0][1][q])) - 1.0f;
                const float oq = __builtin_amdgcn_rcpf(1.0f + __builtin_amdgcn_exp2f(acc[0][2][q]));
                const float cq = fq * cst[0][q] + iv[0][q] * gq;
                cst[0][q] = cq;
                const float th = 2.0f * __builtin_amdgcn_rcpf(1.0f + __builtin_amdgcn_exp2f(SF2 * cq)) - 1.0f;
                pk[q] = (short)f2bf(oq * th);
            }
            *(bf16x4*)&hw[woff[0]] = pk;
        }

        // ================= ct = 1 ============================================
#pragma unroll
        for (int g = 0; g < 3; ++g)
            acc[1][g] = __builtin_amdgcn_mfma_f32_16x16x32_bf16(
                expand4(wX[1][g]), xf, z4, 0, 0, 0);
#pragma unroll
        for (int kt = 0; kt < 8; ++kt) {
            const bf16x8 wo1 = wobase[kt * 256 + 16];            // imm kt*4096+256
            acc[1][0] = __builtin_amdgcn_mfma_f32_16x16x32_bf16(wA[kt][1][0], hb[kt], acc[1][0], 0, 0, 0);
            acc[1][1] = __builtin_amdgcn_mfma_f32_16x16x32_bf16(wA[kt][1][1], hb[kt], acc[1][1], 0, 0, 0);
            acc[1][2] = __builtin_amdgcn_mfma_f32_16x16x32_bf16(wo1,          hb[kt], acc[1][2], 0, 0, 0);
        }
        {
            bf16x4 pk;
#pragma unroll
            for (int q = 0; q < 4; ++q) {
                const float fq = __builtin_amdgcn_rcpf(1.0f + __builtin_amdgcn_exp2f(acc[1][0][q]));
                const float gq = 2.0f * __builtin_amdgcn_rcpf(1.0f + __builtin_amdgcn_exp2f(acc[1][1][q])) - 1.0f;
                const float oq = __builtin_amdgcn_rcpf(1.0f + __builtin_amdgcn_exp2f(acc[1][2][q]));
                const float cq = fq * cst[1][q] + iv[1][q] * gq;
                cst[1][q] = cq;
                const float th = 2.0f * __builtin_amdgcn_rcpf(1.0f + __builtin_amdgcn_exp2f(SF2 * cq)) - 1.0f;
                pk[q] = (short)f2bf(oq * th);
            }
            *(bf16x4*)&hw[woff[1]] = pk;
        }
        __syncthreads();
    }

    // ---- head: out[r] = sum_c h[r][c] w_head[c] + b_head ----
    float p = 0.0f;
    const unsigned short* hf = hbuf[1];   // t=364: cur=0, wrote hbuf[1]
#pragma unroll
    for (int ct = 0; ct < 2; ++ct) {
        const int c0 = wbase + ct * 16 + l16 * 4;
        const f32x4 wh = *(const f32x4*)&w_head[c0];
        const bf16x4 hv = *(const bf16x4*)&hf[woff[ct]];
#pragma unroll
        for (int q = 0; q < 4; ++q) p += bf2f((unsigned short)hv[q]) * wh[q];
    }
    p += __shfl_xor(p, 16);
    p += __shfl_xor(p, 32);
    if (lane < 16) red[wv][m] = p;
    __syncthreads();
    if (tid < ROWS) {
        float s = b_head[0];
#pragma unroll
        for (int w = 0; w < NW; ++w) s += red[w][tid];
        out[rb + tid] = s;
    }
}

extern "C" void kernel_launch(void* const* d_in, const int* in_sizes, int n_in,
                              void* d_out, int out_size, void* d_ws, size_t ws_size,
                              hipStream_t stream)
{
    const float* x_dyn  = (const float*)d_in[0];
    const float* x_stat = (const float*)d_in[1];
    const float* w_i    = (const float*)d_in[2];
    const float* b_i    = (const float*)d_in[3];
    const float* w_f    = (const float*)d_in[4];
    const float* b_f    = (const float*)d_in[5];
    const float* w_g    = (const float*)d_in[6];
    const float* b_g    = (const float*)d_in[7];
    const float* w_o    = (const float*)d_in[8];
    const float* b_o    = (const float*)d_in[9];
    const float* w_head = (const float*)d_in[10];
    const float* b_head = (const float*)d_in[11];

    unsigned short* xg = (unsigned short*)d_ws;   // 64*365*64*2 B = 2.99 MB

    xstage<<<dim3(64), dim3(256), 0, stream>>>(x_dyn, xg);
    ealstm_fused<<<dim3(64), dim3(512), 0, stream>>>(
        xg, x_stat, w_i, b_i, w_f, b_f, w_g, b_g, w_o, b_o,
        w_head, b_head, (float*)d_out);
}